// Round 1
// baseline (203.245 us; speedup 1.0000x reference)
//
#include <hip/hip_runtime.h>
#include <math.h>

#define D_PROJ 8192
#define C_IN   512
#define P_SP   196   // 14*14
#define NBATCH 32

// ---------------------------------------------------------------------------
// Recover count-sketch (h, s) from the dense [512, 8192] matrix: each row has
// exactly one nonzero (value +-1) at column h[row].
// ---------------------------------------------------------------------------
__global__ __launch_bounds__(256) void extract_sketch(
    const float* __restrict__ S, int* __restrict__ h, float* __restrict__ s)
{
    const int row = blockIdx.x;            // 0..511
    const float* rp = S + (size_t)row * D_PROJ;
    for (int c = threadIdx.x; c < D_PROJ; c += 256) {
        float v = rp[c];
        if (v != 0.0f) { h[row] = c; s[row] = v; }   // exactly one thread writes
    }
}

// ---------------------------------------------------------------------------
// Fused Gram + count-sketch-of-outer-product scatter.
// Block = (j_tile, i_tile, batch); computes G tile [128 x 128] with 8x8
// register blocking over P=196 (14 chunks of 14), then scatters
// s1[i]*s2[j]*G[i,j] into an 8192-bin LDS histogram at bin (h1[i]+h2[j])&8191,
// finally flushed with global fp32 atomics into pool (= d_out).
// ---------------------------------------------------------------------------
#define PCH 14           // P chunk
#define LDA 132          // padded LDS row stride (floats); 132*4=528 B, 16B-aligned rows

__global__ __launch_bounds__(256) void gram_scatter(
    const float* __restrict__ x,
    const int* __restrict__ h1, const float* __restrict__ s1,
    const int* __restrict__ h2, const float* __restrict__ s2,
    float* __restrict__ pool)
{
    __shared__ float accL[D_PROJ];                       // 32 KB histogram
    __shared__ __align__(16) float As[PCH * LDA];        // 7.4 KB, p-major: As[p][i]
    __shared__ __align__(16) float Bs[PCH * LDA];
    __shared__ int   h1L[128];
    __shared__ float s1L[128];
    __shared__ int   h2L[128];
    __shared__ float s2L[128];

    const int tid = threadIdx.x;
    const int tx  = tid & 15;        // j quad
    const int ty  = tid >> 4;        // i quad
    const int b   = blockIdx.z;
    const int it  = blockIdx.y;      // i tile (0..3)
    const int jt  = blockIdx.x;      // j tile (0..3)

    if (tid < 128) {
        h1L[tid] = h1[it * 128 + tid];
        s1L[tid] = s1[it * 128 + tid];
        h2L[tid] = h2[jt * 128 + tid];
        s2L[tid] = s2[jt * 128 + tid];
    }
    for (int k = tid; k < D_PROJ; k += 256) accL[k] = 0.0f;

    const float* xi = x + ((size_t)b * C_IN + it * 128) * P_SP;
    const float* xj = x + ((size_t)b * C_IN + jt * 128) * P_SP;

    float acc[8][8];
    #pragma unroll
    for (int r = 0; r < 8; ++r)
        #pragma unroll
        for (int c = 0; c < 8; ++c) acc[r][c] = 0.0f;

    for (int ch = 0; ch < P_SP / PCH; ++ch) {
        const int p0 = ch * PCH;
        __syncthreads();   // also covers histogram zero / param staging on ch==0
        #pragma unroll
        for (int e = 0; e < 7; ++e) {            // 7*256 = 1792 = 128*14 loads each
            int idx = e * 256 + tid;
            int il  = idx / PCH;
            int pp  = idx - il * PCH;
            As[pp * LDA + il] = xi[il * P_SP + p0 + pp];
            Bs[pp * LDA + il] = xj[il * P_SP + p0 + pp];
        }
        __syncthreads();
        #pragma unroll
        for (int pp = 0; pp < PCH; ++pp) {
            const float* ap = &As[pp * LDA];
            const float* bp = &Bs[pp * LDA];
            float4 a0 = *(const float4*)(ap + ty * 4);
            float4 a1 = *(const float4*)(ap + 64 + ty * 4);
            float4 b0 = *(const float4*)(bp + tx * 4);
            float4 b1 = *(const float4*)(bp + 64 + tx * 4);
            float av[8] = {a0.x, a0.y, a0.z, a0.w, a1.x, a1.y, a1.z, a1.w};
            float bv[8] = {b0.x, b0.y, b0.z, b0.w, b1.x, b1.y, b1.z, b1.w};
            #pragma unroll
            for (int r = 0; r < 8; ++r)
                #pragma unroll
                for (int c = 0; c < 8; ++c)
                    acc[r][c] = fmaf(av[r], bv[c], acc[r][c]);
        }
    }

    // Scatter the G tile through the count-sketch into the LDS histogram.
    #pragma unroll
    for (int r = 0; r < 8; ++r) {
        int   il = (r < 4) ? (ty * 4 + r) : (64 + ty * 4 + (r - 4));
        int   hA = h1L[il];
        float sA = s1L[il];
        #pragma unroll
        for (int c = 0; c < 8; ++c) {
            int jl = (c < 4) ? (tx * 4 + c) : (64 + tx * 4 + (c - 4));
            int d  = (hA + h2L[jl]) & (D_PROJ - 1);
            atomicAdd(&accL[d], sA * s2L[jl] * acc[r][c]);
        }
    }
    __syncthreads();

    float* pb = pool + (size_t)b * D_PROJ;
    for (int k = tid; k < D_PROJ; k += 256) atomicAdd(&pb[k], accL[k]);
}

// ---------------------------------------------------------------------------
// Per-batch: norm^2 = sum(|pool|) + 8192e-8; out = sign(p)*sqrt(|p|+1e-8)/norm
// In-place on d_out (pool was accumulated there).
// ---------------------------------------------------------------------------
__global__ __launch_bounds__(256) void finalize_kernel(float* __restrict__ out)
{
    const int b = blockIdx.x;
    float* p = out + (size_t)b * D_PROJ;
    const int tid = threadIdx.x;

    float s = 0.0f;
    for (int d = tid; d < D_PROJ; d += 256) s += fabsf(p[d]);
    #pragma unroll
    for (int off = 32; off > 0; off >>= 1) s += __shfl_down(s, off, 64);

    __shared__ float red[4];
    if ((tid & 63) == 0) red[tid >> 6] = s;
    __syncthreads();
    float total = red[0] + red[1] + red[2] + red[3];
    float norm  = fmaxf(sqrtf(total + (float)D_PROJ * 1e-8f), 1e-12f);
    float inv   = 1.0f / norm;

    for (int d = tid; d < D_PROJ; d += 256) {
        float v = p[d];
        float r = sqrtf(fabsf(v) + 1e-8f) * inv;
        p[d] = (v > 0.0f) ? r : ((v < 0.0f) ? -r : 0.0f);
    }
}

// ---------------------------------------------------------------------------
extern "C" void kernel_launch(void* const* d_in, const int* in_sizes, int n_in,
                              void* d_out, int out_size, void* d_ws, size_t ws_size,
                              hipStream_t stream)
{
    const float* x  = (const float*)d_in[0];   // [32, 512, 14, 14]
    const float* S1 = (const float*)d_in[1];   // [512, 8192]
    const float* S2 = (const float*)d_in[2];   // [512, 8192]
    float* out = (float*)d_out;                // [32, 8192]

    char* ws = (char*)d_ws;                    // only 8 KB used
    int*   h1 = (int*)(ws);
    float* s1 = (float*)(ws + 2048);
    int*   h2 = (int*)(ws + 4096);
    float* s2 = (float*)(ws + 6144);

    hipMemsetAsync(d_out, 0, (size_t)out_size * sizeof(float), stream);
    extract_sketch<<<512, 256, 0, stream>>>(S1, h1, s1);
    extract_sketch<<<512, 256, 0, stream>>>(S2, h2, s2);
    gram_scatter<<<dim3(4, 4, NBATCH), 256, 0, stream>>>(x, h1, s1, h2, s2, out);
    finalize_kernel<<<NBATCH, 256, 0, stream>>>(out);
}